// Round 1
// baseline (7268.045 us; speedup 1.0000x reference)
//
#include <hip/hip_runtime.h>
#include <hip/hip_bf16.h>

#define BATCH 16384
#define TSTEPS 101
#define HDIM 512
#define GDIM 2048  // 4*H

typedef __attribute__((ext_vector_type(8))) short s16x8;
typedef __attribute__((ext_vector_type(4))) float f32x4;

__device__ __forceinline__ float sigm(float x){ return 1.0f/(1.0f + __expf(-x)); }
__device__ __forceinline__ float tanhx(float x){ float e=__expf(2.0f*x); return 1.0f - 2.0f/(e+1.0f); }

__device__ __forceinline__ void gload16(const void* g, void* l){
  __builtin_amdgcn_global_load_lds((const __attribute__((address_space(1))) unsigned int*)g,
                                   (__attribute__((address_space(3))) unsigned int*)l, 16, 0, 0);
}

// gates = hin @ W_hh^T (+ x_t @ W_ih^T + b), then LSTM cell update.
// grid (128, 16): blockIdx.x -> 128 batch rows, blockIdx.y -> 32 per-gate cols.
// Each block computes 4 gate tiles (i,f,g,o) of 128x32, K=512.
__global__ __launch_bounds__(256) void lstm_step(
    const __hip_bfloat16* __restrict__ hin,
    __hip_bfloat16* __restrict__ hout,
    float* __restrict__ cbuf,
    const float* __restrict__ bx,
    const float* __restrict__ Wih,
    const float* __restrict__ bcomb,
    const __hip_bfloat16* __restrict__ wbf,
    float* __restrict__ h32,
    int t, int skipmm, int wh32)
{
  __shared__ short sA[128*64];   // h tile, XOR-swizzled within each 128B row
  __shared__ short sB[128*64];   // 4 gates x 32 rows of W_hh, same swizzle
  const int tid = threadIdx.x;
  const int l = tid & 63, w = tid >> 6;
  const int lr = l & 15, lk = l >> 4;
  const int m0 = blockIdx.x * 128;
  const int j0 = blockIdx.y * 32;

  f32x4 acc[4][2][2] = {};

  if (!skipmm){
    for (int k0 = 0; k0 < HDIM; k0 += 64){
      __syncthreads();
      // stage A: 128 rows x 64 cols bf16 = 1024 x 16B chunks. LDS linear, source pre-swizzled.
      #pragma unroll
      for (int i = 0; i < 4; ++i){
        int cch = i*256 + tid;
        int row = cch >> 3, kc = cch & 7;
        int kcs = kc ^ (row & 7);
        gload16(hin + (size_t)(m0 + row)*HDIM + k0 + kcs*8, &sA[cch*8]);
      }
      // stage B: 4 gates x 32 rows x 64 cols
      #pragma unroll
      for (int i = 0; i < 4; ++i){
        int cch = i*256 + tid;
        int r = cch >> 3, kc = cch & 7;
        int kcs = kc ^ (r & 7);
        int wrow = (r >> 5)*HDIM + j0 + (r & 31);   // gate*512 + j0 + row-in-gate
        gload16(wbf + (size_t)wrow*HDIM + k0 + kcs*8, &sB[cch*8]);
      }
      __syncthreads();
      #pragma unroll
      for (int kk = 0; kk < 2; ++kk){
        s16x8 av[2];
        #pragma unroll
        for (int m = 0; m < 2; ++m){
          int row = w*32 + m*16 + lr;
          int slot = row*8 + ((kk*4 + lk) ^ (row & 7));
          av[m] = *(const s16x8*)&sA[slot*8];
        }
        #pragma unroll
        for (int g = 0; g < 4; ++g){
          #pragma unroll
          for (int n = 0; n < 2; ++n){
            int rB = g*32 + n*16 + lr;
            int slot = rB*8 + ((kk*4 + lk) ^ (rB & 7));
            s16x8 bv = *(const s16x8*)&sB[slot*8];
            acc[g][0][n] = __builtin_amdgcn_mfma_f32_16x16x32_bf16(av[0], bv, acc[g][0][n], 0, 0, 0);
            acc[g][1][n] = __builtin_amdgcn_mfma_f32_16x16x32_bf16(av[1], bv, acc[g][1][n], 0, 0, 0);
          }
        }
      }
    }
  }

  // Epilogue: add x-projection + bias, apply cell update.
  // C/D mapping (m89): col = lane&15, row = (lane>>4)*4 + reg.
  float4 wv[4][2]; float bc[4][2];
  #pragma unroll
  for (int g = 0; g < 4; ++g){
    #pragma unroll
    for (int n = 0; n < 2; ++n){
      int col = j0 + n*16 + lr;
      int grow = g*HDIM + col;
      wv[g][n] = *(const float4*)(Wih + (size_t)grow*4);
      bc[g][n] = bcomb[grow];
    }
  }
  #pragma unroll
  for (int m = 0; m < 2; ++m){
    #pragma unroll
    for (int rg = 0; rg < 4; ++rg){
      int r = m0 + w*32 + m*16 + lk*4 + rg;
      float4 xv = *(const float4*)(bx + ((size_t)r*TSTEPS + t)*4);
      #pragma unroll
      for (int n = 0; n < 2; ++n){
        int col = j0 + n*16 + lr;
        float pi = acc[0][m][n][rg] + bc[0][n] + xv.x*wv[0][n].x + xv.y*wv[0][n].y + xv.z*wv[0][n].z + xv.w*wv[0][n].w;
        float pf = acc[1][m][n][rg] + bc[1][n] + xv.x*wv[1][n].x + xv.y*wv[1][n].y + xv.z*wv[1][n].z + xv.w*wv[1][n].w;
        float pg = acc[2][m][n][rg] + bc[2][n] + xv.x*wv[2][n].x + xv.y*wv[2][n].y + xv.z*wv[2][n].z + xv.w*wv[2][n].w;
        float po = acc[3][m][n][rg] + bc[3][n] + xv.x*wv[3][n].x + xv.y*wv[3][n].y + xv.z*wv[3][n].z + xv.w*wv[3][n].w;
        float iv = sigm(pi), fv = sigm(pf), gv = tanhx(pg), ov = sigm(po);
        size_t idx = (size_t)r*HDIM + col;
        float cn = fv*cbuf[idx] + iv*gv;
        cbuf[idx] = cn;
        float hn = ov*tanhx(cn);
        hout[idx] = __float2bfloat16(hn);
        if (wh32) h32[idx] = hn;
      }
    }
  }
}

__global__ void prep(const float* __restrict__ Whh, const float* __restrict__ bih,
                     const float* __restrict__ bhh,
                     __hip_bfloat16* __restrict__ wbf, float* __restrict__ bcomb){
  int i = blockIdx.x*256 + threadIdx.x;
  if (i < GDIM*HDIM) wbf[i] = __float2bfloat16(Whh[i]);
  if (i < GDIM) bcomb[i] = bih[i] + bhh[i];
}

// x = relu(h32 @ W1^T + b1), fp32, 64x64 tiles
__global__ __launch_bounds__(256) void mlp1(const float* __restrict__ h32, const float* __restrict__ W1,
                                            const float* __restrict__ b1, float* __restrict__ xout){
  __shared__ float sA[64][17];
  __shared__ float sB[64][17];
  const int tid = threadIdx.x;
  const int r0 = blockIdx.x*64, c0 = blockIdx.y*64;
  const int tx = tid & 15, ty = tid >> 4;
  float acc[4][4] = {};
  for (int k0 = 0; k0 < HDIM; k0 += 16){
    __syncthreads();
    #pragma unroll
    for (int i = 0; i < 4; ++i){
      int id = i*256 + tid;
      int rr = id >> 4, cc = id & 15;
      sA[rr][cc] = h32[(size_t)(r0+rr)*HDIM + k0 + cc];
      sB[rr][cc] = W1[(size_t)(c0+rr)*HDIM + k0 + cc];
    }
    __syncthreads();
    #pragma unroll
    for (int kk = 0; kk < 16; ++kk){
      float a[4], b[4];
      #pragma unroll
      for (int ii = 0; ii < 4; ++ii) a[ii] = sA[ty*4+ii][kk];
      #pragma unroll
      for (int jj = 0; jj < 4; ++jj) b[jj] = sB[tx*4+jj][kk];
      #pragma unroll
      for (int ii = 0; ii < 4; ++ii)
        #pragma unroll
        for (int jj = 0; jj < 4; ++jj) acc[ii][jj] += a[ii]*b[jj];
    }
  }
  #pragma unroll
  for (int ii = 0; ii < 4; ++ii){
    #pragma unroll
    for (int jj = 0; jj < 4; ++jj){
      int r = r0 + ty*4 + ii, c = c0 + tx*4 + jj;
      float v = acc[ii][jj] + b1[c];
      xout[(size_t)r*HDIM + c] = v > 0.f ? v : 0.f;
    }
  }
}

// out[b] = x[b,:] . W2[0:512] + a[b]*W2[512] + b2 ; one wave per row
__global__ __launch_bounds__(256) void mlp2(const float* __restrict__ x, const float* __restrict__ a,
                                            const float* __restrict__ W2, const float* __restrict__ b2,
                                            float* __restrict__ out){
  const int wi = threadIdx.x >> 6, l = threadIdx.x & 63;
  const int b = blockIdx.x*4 + wi;
  const float* xr = x + (size_t)b*HDIM;
  float4 v0 = *(const float4*)(xr + l*8);
  float4 v1 = *(const float4*)(xr + l*8 + 4);
  float4 w0 = *(const float4*)(W2 + l*8);
  float4 w1 = *(const float4*)(W2 + l*8 + 4);
  float s = v0.x*w0.x + v0.y*w0.y + v0.z*w0.z + v0.w*w0.w
          + v1.x*w1.x + v1.y*w1.y + v1.z*w1.z + v1.w*w1.w;
  #pragma unroll
  for (int off = 32; off > 0; off >>= 1) s += __shfl_down(s, off);
  if (l == 0) out[b] = s + a[b]*W2[HDIM] + b2[0];
}

extern "C" void kernel_launch(void* const* d_in, const int* in_sizes, int n_in,
                              void* d_out, int out_size, void* d_ws, size_t ws_size,
                              hipStream_t stream){
  const float* bx  = (const float*)d_in[0];
  const float* ba  = (const float*)d_in[1];
  const float* Wih = (const float*)d_in[2];
  const float* Whh = (const float*)d_in[3];
  const float* bih = (const float*)d_in[4];
  const float* bhh = (const float*)d_in[5];
  const float* W1  = (const float*)d_in[6];
  const float* b1  = (const float*)d_in[7];
  const float* W2  = (const float*)d_in[8];
  const float* b2  = (const float*)d_in[9];
  float* out = (float*)d_out;

  char* ws = (char*)d_ws;
  __hip_bfloat16* wbf   = (__hip_bfloat16*)(ws);              // 2 MB
  float*          bcomb = (float*)(ws + 2097152);             // 8 KB
  __hip_bfloat16* hb0   = (__hip_bfloat16*)(ws + 2105344);    // 16 MB
  __hip_bfloat16* hb1   = (__hip_bfloat16*)(ws + 18882560);   // 16 MB
  float*          cbuf  = (float*)(ws + 35659776);            // 32 MB
  float*          h32   = (float*)(ws + 69214208);            // 32 MB  (end ~98 MB)
  float*          xmlp  = cbuf;  // c is dead after last step; reuse for MLP activations

  prep<<<4096, 256, 0, stream>>>(Whh, bih, bhh, wbf, bcomb);
  hipMemsetAsync(cbuf, 0, (size_t)BATCH*HDIM*sizeof(float), stream);

  for (int t = 0; t < TSTEPS; ++t){
    const __hip_bfloat16* hin = (t & 1) ? hb1 : hb0;
    __hip_bfloat16*      hout = (t & 1) ? hb0 : hb1;
    lstm_step<<<dim3(128, 16), 256, 0, stream>>>(hin, hout, cbuf, bx, Wih, bcomb, wbf, h32,
                                                 t, (t == 0) ? 1 : 0, (t == TSTEPS-1) ? 1 : 0);
  }
  mlp1<<<dim3(256, 8), 256, 0, stream>>>(h32, W1, b1, xmlp);
  mlp2<<<4096, 256, 0, stream>>>(xmlp, ba, W2, b2, out);
}

// Round 2
// 5675.808 us; speedup vs baseline: 1.2805x; 1.2805x over previous
//
#include <hip/hip_runtime.h>
#include <hip/hip_bf16.h>

#define BATCH 16384
#define TSTEPS 101
#define HDIM 512
#define GDIM 2048  // 4*H

typedef __attribute__((ext_vector_type(8))) short s16x8;
typedef __attribute__((ext_vector_type(4))) float f32x4;

__device__ __forceinline__ float sigm(float x){ return 1.0f/(1.0f + __expf(-x)); }
__device__ __forceinline__ float tanhx(float x){ float e=__expf(2.0f*x); return 1.0f - 2.0f/(e+1.0f); }

__device__ __forceinline__ void gload16(const void* g, void* l){
  __builtin_amdgcn_global_load_lds((const __attribute__((address_space(1))) unsigned int*)g,
                                   (__attribute__((address_space(3))) unsigned int*)l, 16, 0, 0);
}

// gates = hin @ W_hh^T (+ x_t @ W_ih^T + b), then LSTM cell update.
// 1-D grid of 1024 blocks, XCD-chunked: 64 row-panels (256 rows) x 16 col-blocks (32 cols/gate).
// Each block: 256x128 output tile (4 gates x 32 cols), 4 waves of 64 rows x 128 cols.
__global__ __launch_bounds__(256, 2) void lstm_step(
    const __hip_bfloat16* __restrict__ hin,
    __hip_bfloat16* __restrict__ hout,
    float* __restrict__ cbuf,
    const float* __restrict__ bx,
    const float* __restrict__ Wih,
    const float* __restrict__ bcomb,
    const __hip_bfloat16* __restrict__ wbf,
    int t, int skipmm)
{
  __shared__ short sA[256*64];   // h tile (256 rows x 64 k), XOR-swizzled per 128B row
  __shared__ short sB[128*64];   // 4 gates x 32 rows of W_hh, same swizzle
  const int tid = threadIdx.x;
  const int l = tid & 63, w = tid >> 6;
  const int lr = l & 15, lk = l >> 4;

  // XCD-chunked swizzle: consecutive swz land on one XCD; col-block fastest.
  const int orig = blockIdx.x;
  const int swz = (orig & 7)*128 + (orig >> 3);
  const int m0 = (swz >> 4) * 256;       // row-panel
  const int j0 = (swz & 15) * 32;        // per-gate col offset

  f32x4 acc[4][4][2] = {};  // [gate][m(4x16 rows)][n(2x16 cols)]

  if (!skipmm){
    for (int k0 = 0; k0 < HDIM; k0 += 64){
      __syncthreads();
      // stage A: 256 rows x 64 cols bf16 = 2048 x 16B chunks
      #pragma unroll
      for (int i = 0; i < 8; ++i){
        int cch = i*256 + tid;
        int row = cch >> 3, kc = cch & 7;
        int kcs = kc ^ (row & 7);
        gload16(hin + (size_t)(m0 + row)*HDIM + k0 + kcs*8, &sA[cch*8]);
      }
      // stage B: 4 gates x 32 rows x 64 cols = 1024 chunks
      #pragma unroll
      for (int i = 0; i < 4; ++i){
        int cch = i*256 + tid;
        int r = cch >> 3, kc = cch & 7;
        int kcs = kc ^ (r & 7);
        int wrow = (r >> 5)*HDIM + j0 + (r & 31);   // gate*512 + j0 + row-in-gate
        gload16(wbf + (size_t)wrow*HDIM + k0 + kcs*8, &sB[cch*8]);
      }
      __syncthreads();
      #pragma unroll
      for (int kk = 0; kk < 2; ++kk){
        s16x8 av[4];
        #pragma unroll
        for (int m = 0; m < 4; ++m){
          int row = w*64 + m*16 + lr;
          int slot = row*8 + ((kk*4 + lk) ^ (row & 7));
          av[m] = *(const s16x8*)&sA[slot*8];
        }
        #pragma unroll
        for (int g = 0; g < 4; ++g){
          #pragma unroll
          for (int n = 0; n < 2; ++n){
            int rB = g*32 + n*16 + lr;
            int slot = rB*8 + ((kk*4 + lk) ^ (rB & 7));
            s16x8 bv = *(const s16x8*)&sB[slot*8];
            #pragma unroll
            for (int m = 0; m < 4; ++m)
              acc[g][m][n] = __builtin_amdgcn_mfma_f32_16x16x32_bf16(av[m], bv, acc[g][m][n], 0, 0, 0);
          }
        }
      }
    }
  }

  // Epilogue: add x-projection + bias, apply cell update.
  // C/D mapping (m89): col = lane&15, row = (lane>>4)*4 + reg.
  float4 wv[4][2]; float bc[4][2];
  #pragma unroll
  for (int g = 0; g < 4; ++g){
    #pragma unroll
    for (int n = 0; n < 2; ++n){
      int col = j0 + n*16 + lr;
      int grow = g*HDIM + col;
      wv[g][n] = *(const float4*)(Wih + (size_t)grow*4);
      bc[g][n] = bcomb[grow];
    }
  }
  #pragma unroll
  for (int m = 0; m < 4; ++m){
    #pragma unroll
    for (int rg = 0; rg < 4; ++rg){
      int r = m0 + w*64 + m*16 + lk*4 + rg;
      float4 xv = *(const float4*)(bx + ((size_t)r*TSTEPS + t)*4);
      #pragma unroll
      for (int n = 0; n < 2; ++n){
        int col = j0 + n*16 + lr;
        float pi = acc[0][m][n][rg] + bc[0][n] + xv.x*wv[0][n].x + xv.y*wv[0][n].y + xv.z*wv[0][n].z + xv.w*wv[0][n].w;
        float pf = acc[1][m][n][rg] + bc[1][n] + xv.x*wv[1][n].x + xv.y*wv[1][n].y + xv.z*wv[1][n].z + xv.w*wv[1][n].w;
        float pg = acc[2][m][n][rg] + bc[2][n] + xv.x*wv[2][n].x + xv.y*wv[2][n].y + xv.z*wv[2][n].z + xv.w*wv[2][n].w;
        float po = acc[3][m][n][rg] + bc[3][n] + xv.x*wv[3][n].x + xv.y*wv[3][n].y + xv.z*wv[3][n].z + xv.w*wv[3][n].w;
        float iv = sigm(pi), fv = sigm(pf), gv = tanhx(pg), ov = sigm(po);
        size_t idx = (size_t)r*HDIM + col;
        float cn = fv*cbuf[idx] + iv*gv;
        cbuf[idx] = cn;
        hout[idx] = __float2bfloat16(ov*tanhx(cn));
      }
    }
  }
}

__global__ void prep(const float* __restrict__ Whh, const float* __restrict__ W1,
                     const float* __restrict__ bih, const float* __restrict__ bhh,
                     __hip_bfloat16* __restrict__ wbf, __hip_bfloat16* __restrict__ w1bf,
                     float* __restrict__ bcomb){
  int i = blockIdx.x*256 + threadIdx.x;
  if (i < GDIM*HDIM) wbf[i] = __float2bfloat16(Whh[i]);
  if (i < HDIM*HDIM) w1bf[i] = __float2bfloat16(W1[i]);
  if (i < GDIM) bcomb[i] = bih[i] + bhh[i];
}

// x = relu(hT @ W1^T + b1), bf16 MFMA, fp32 out. Block 128x128, wave 32x128.
__global__ __launch_bounds__(256) void mlp1(const __hip_bfloat16* __restrict__ hT,
                                            const __hip_bfloat16* __restrict__ w1bf,
                                            const float* __restrict__ b1, float* __restrict__ xout){
  __shared__ short sA[128*64];
  __shared__ short sB[128*64];
  const int tid = threadIdx.x;
  const int l = tid & 63, w = tid >> 6;
  const int lr = l & 15, lk = l >> 4;
  const int r0 = blockIdx.x * 128, c0 = blockIdx.y * 128;

  f32x4 acc[2][8] = {};
  for (int k0 = 0; k0 < HDIM; k0 += 64){
    __syncthreads();
    #pragma unroll
    for (int i = 0; i < 4; ++i){
      int cch = i*256 + tid;
      int row = cch >> 3, kc = cch & 7;
      int kcs = kc ^ (row & 7);
      gload16(hT + (size_t)(r0 + row)*HDIM + k0 + kcs*8, &sA[cch*8]);
    }
    #pragma unroll
    for (int i = 0; i < 4; ++i){
      int cch = i*256 + tid;
      int row = cch >> 3, kc = cch & 7;
      int kcs = kc ^ (row & 7);
      gload16(w1bf + (size_t)(c0 + row)*HDIM + k0 + kcs*8, &sB[cch*8]);
    }
    __syncthreads();
    #pragma unroll
    for (int kk = 0; kk < 2; ++kk){
      s16x8 av[2];
      #pragma unroll
      for (int m = 0; m < 2; ++m){
        int row = w*32 + m*16 + lr;
        int slot = row*8 + ((kk*4 + lk) ^ (row & 7));
        av[m] = *(const s16x8*)&sA[slot*8];
      }
      #pragma unroll
      for (int n = 0; n < 8; ++n){
        int rB = n*16 + lr;
        int slot = rB*8 + ((kk*4 + lk) ^ (rB & 7));
        s16x8 bv = *(const s16x8*)&sB[slot*8];
        #pragma unroll
        for (int m = 0; m < 2; ++m)
          acc[m][n] = __builtin_amdgcn_mfma_f32_16x16x32_bf16(av[m], bv, acc[m][n], 0, 0, 0);
      }
    }
  }
  #pragma unroll
  for (int m = 0; m < 2; ++m){
    #pragma unroll
    for (int rg = 0; rg < 4; ++rg){
      int r = r0 + w*32 + m*16 + lk*4 + rg;
      #pragma unroll
      for (int n = 0; n < 8; ++n){
        int c = c0 + n*16 + lr;
        float v = acc[m][n][rg] + b1[c];
        xout[(size_t)r*HDIM + c] = v > 0.f ? v : 0.f;
      }
    }
  }
}

// out[b] = x[b,:] . W2[0:512] + a[b]*W2[512] + b2 ; one wave per row
__global__ __launch_bounds__(256) void mlp2(const float* __restrict__ x, const float* __restrict__ a,
                                            const float* __restrict__ W2, const float* __restrict__ b2,
                                            float* __restrict__ out){
  const int wi = threadIdx.x >> 6, l = threadIdx.x & 63;
  const int b = blockIdx.x*4 + wi;
  const float* xr = x + (size_t)b*HDIM;
  float4 v0 = *(const float4*)(xr + l*8);
  float4 v1 = *(const float4*)(xr + l*8 + 4);
  float4 w0 = *(const float4*)(W2 + l*8);
  float4 w1 = *(const float4*)(W2 + l*8 + 4);
  float s = v0.x*w0.x + v0.y*w0.y + v0.z*w0.z + v0.w*w0.w
          + v1.x*w1.x + v1.y*w1.y + v1.z*w1.z + v1.w*w1.w;
  #pragma unroll
  for (int off = 32; off > 0; off >>= 1) s += __shfl_down(s, off);
  if (l == 0) out[b] = s + a[b]*W2[HDIM] + b2[0];
}

extern "C" void kernel_launch(void* const* d_in, const int* in_sizes, int n_in,
                              void* d_out, int out_size, void* d_ws, size_t ws_size,
                              hipStream_t stream){
  const float* bx  = (const float*)d_in[0];
  const float* ba  = (const float*)d_in[1];
  const float* Wih = (const float*)d_in[2];
  const float* Whh = (const float*)d_in[3];
  const float* bih = (const float*)d_in[4];
  const float* bhh = (const float*)d_in[5];
  const float* W1  = (const float*)d_in[6];
  const float* b1  = (const float*)d_in[7];
  const float* W2  = (const float*)d_in[8];
  const float* b2  = (const float*)d_in[9];
  float* out = (float*)d_out;

  char* ws = (char*)d_ws;
  __hip_bfloat16* wbf   = (__hip_bfloat16*)(ws);              // 2 MB
  __hip_bfloat16* w1bf  = (__hip_bfloat16*)(ws + 2097152);    // 512 KB
  float*          bcomb = (float*)(ws + 2621440);             // 8 KB
  __hip_bfloat16* hb0   = (__hip_bfloat16*)(ws + 2629632);    // 16 MB
  __hip_bfloat16* hb1   = (__hip_bfloat16*)(ws + 19406848);   // 16 MB
  float*          cbuf  = (float*)(ws + 36184064);            // 32 MB (end ~66.5 MB)
  float*          xmlp  = cbuf;  // c dead after last step; reuse for MLP activations

  prep<<<4096, 256, 0, stream>>>(Whh, W1, bih, bhh, wbf, w1bf, bcomb);
  hipMemsetAsync(cbuf, 0, (size_t)BATCH*HDIM*sizeof(float), stream);

  for (int t = 0; t < TSTEPS; ++t){
    const __hip_bfloat16* hin = (t & 1) ? hb1 : hb0;
    __hip_bfloat16*      hout = (t & 1) ? hb0 : hb1;
    lstm_step<<<1024, 256, 0, stream>>>(hin, hout, cbuf, bx, Wih, bcomb, wbf,
                                        t, (t == 0) ? 1 : 0);
  }
  // t=100 wrote hout = hb1
  mlp1<<<dim3(128, 4), 256, 0, stream>>>(hb1, w1bf, b1, xmlp);
  mlp2<<<4096, 256, 0, stream>>>(xmlp, ba, W2, b2, out);
}